// Round 10
// baseline (130.469 us; speedup 1.0000x reference)
//
#include <hip/hip_runtime.h>
#include <hip/hip_bf16.h>
#include <cfloat>

// B=32, N=2048 -> BN=65536 rows, D=128, K=1024 codes
#define DIM 128
#define NCODES 1024
#define MTILE 128            // rows per block = 4 waves x 32 rows
#define ROWS_PER_WAVE 32
#define NSUB 2               // 16-row M-subtiles per wave
#define KSTEPS 4             // K=128 / 32
#define CODES_PER_TILE 16    // codes per step tile
#define NSTEPS 64            // 1024 codes / 16
#define TILE_F16 4096        // f16 elems per 16-code tile (8 KB: hi 2048 + lo 2048)
#define TILE_BYTES 8192
#define LOSS_SCALE (12.5f / 8388608.0f)

typedef _Float16 f16x8 __attribute__((ext_vector_type(8)));
typedef float f32x4 __attribute__((ext_vector_type(4)));

// prep: E (fp32) -> Epk (packed fragment-linear f16 hi/lo image) + enorm.
// Tile g = k>>4 holds codes g*16..g*16+15. Within a tile (f16 units):
//   addr = g*4096 + plane*2048 + ks*512 + (quad*16 + m16)*8 + j
// (ks=d>>5, quad=(d>>3)&3, j=d&7) so vq's lane l=quad*16+m16 loads its 16 B at
// tile_base + plane*4096B + ks*1024B + l*16 -> one contiguous, coalesced 1 KB
// global_load_dwordx4 per (plane,ks). Block 0 zeroes loss.
__global__ __launch_bounds__(128) void prep_kernel(const float* __restrict__ E,
                                                   _Float16* __restrict__ Epk,
                                                   float* __restrict__ enorm,
                                                   float* __restrict__ loss) {
    const int k = blockIdx.x;   // code
    const int d = threadIdx.x;  // dim
    if (k == 0 && d == 0) *loss = 0.f;
    float e = E[k * DIM + d];
    _Float16 h = (_Float16)e;
    _Float16 l = (_Float16)(e - (float)h);
    const int g = k >> 4;
    const int m16 = k & 15;
    const int ks = d >> 5, quad = (d >> 3) & 3, j = d & 7;
    const int addr = g * TILE_F16 + ks * 512 + ((quad << 4) + m16) * 8 + j;
    Epk[addr] = h;           // hi plane
    Epk[addr + 2048] = l;    // lo plane
    float sq = e * e;
#pragma unroll
    for (int off = 32; off > 0; off >>= 1) sq += __shfl_down(sq, off, 64);
    __shared__ float s2[2];
    if ((d & 63) == 0) s2[d >> 6] = sq;
    __syncthreads();
    if (d == 0) enorm[k] = s2[0] + s2[1];
}

// Fused MFMA dist + argmin + gather + loss.
// r16 (this round): r15's depth-2 prefetch regressed slightly (63 vs 59) ->
// loads land fine at depth 1; the exposed time is NOT a vmem wait. Remaining
// suspect for the matrix pipe idling 58% with resident data: chain ILP.
// r11 feeds 24 MFMAs/step into only 2 accumulator chains (12-deep dependent
// each; hh/hl/lh all accumulate into one register). Same-chain issue spacing
// ~2 slots ~19 cyc at 2 waves/SIMD < MFMA result latency -> every dependent
// issue stalls; 932-cyc issue stream stretches toward the observed 2213.
// (Also retro-explains r12's solo-wave 2381.) Fix: split each acc into its 3
// partial products -> 6 independent chains/wave (hh0,hh1,hl0,hl1,lh0,lh1),
// 12/SIMD, same-chain spacing 6 issues ~29 cyc/wave. Merge = 2 v_adds per
// position at the compare. +16 VGPR, +16 VALU/step. Everything else is
// byte-exact r11 (depth-1 double buffer, zero loop barriers, (256,2)).
// r3 lesson: no runtime-indexed register arrays.
__global__ __launch_bounds__(256, 2) void vq_kernel(const float* __restrict__ z,
                                                    const _Float16* __restrict__ Epk,
                                                    const float* __restrict__ enorm,
                                                    const float* __restrict__ E,
                                                    float* __restrict__ out,
                                                    float* __restrict__ loss) {
    const int t = threadIdx.x;
    const int lane = t & 63;
    const int wave = t >> 6;     // row-wave: rows [wave*32, wave*32+32)
    const int m16 = lane & 15;   // A row within subtile / B,C code col
    const int quad = lane >> 4;  // k-group for A/B; row-group for C

    __shared__ __attribute__((aligned(16))) float s_enorm[NCODES];  // 4 KB
    __shared__ int s_ind[MTILE];
    __shared__ float s_wsum[4];

    // one-time enorm -> LDS (vectorized, 256 thr x 16 B)
    *(float4*)&s_enorm[t * 4] = ((const float4*)enorm)[t];

    // Load step ST's 8 fragment sets (hi+lo x 4 ksteps) from global; each is
    // one coalesced 1 KB global_load_dwordx4 (lane-linear packed layout).
#define LOADF(ST, H, L)                                                              \
    {                                                                                \
        const char* gb = (const char*)Epk + (size_t)(ST)*TILE_BYTES + lane * 16;     \
        H[0] = *(const f16x8*)(gb);                                                  \
        H[1] = *(const f16x8*)(gb + 1024);                                           \
        H[2] = *(const f16x8*)(gb + 2048);                                           \
        H[3] = *(const f16x8*)(gb + 3072);                                           \
        L[0] = *(const f16x8*)(gb + 4096);                                           \
        L[1] = *(const f16x8*)(gb + 5120);                                           \
        L[2] = *(const f16x8*)(gb + 6144);                                           \
        L[3] = *(const f16x8*)(gb + 7168);                                           \
    }

    f16x8 FAh[KSTEPS], FAl[KSTEPS], FBh[KSTEPS], FBl[KSTEPS];
    LOADF(0, FAh, FAl)  // in flight under A-prep below

    // ---- A fragments: this wave's 32 rows, K=128, scaled by -2, f16 hi/lo.
    // A layout (16x16x32): lane holds A[m=lane&15][k=quad*8+j], j=0..7.
    f16x8 Ahi[NSUB][KSTEPS], Alo[NSUB][KSTEPS];
    float znp[NSUB] = {0.f, 0.f};
    const int rowbase = blockIdx.x * MTILE + wave * ROWS_PER_WAVE;
#pragma unroll
    for (int s = 0; s < NSUB; ++s) {
        const int row = rowbase + s * 16 + m16;
        const float* zp = z + (size_t)row * DIM + quad * 8;
#pragma unroll
        for (int ks = 0; ks < KSTEPS; ++ks) {
            float4 v0 = *(const float4*)(zp + ks * 32);
            float4 v1 = *(const float4*)(zp + ks * 32 + 4);
            float zv[8] = {v0.x, v0.y, v0.z, v0.w, v1.x, v1.y, v1.z, v1.w};
#pragma unroll
            for (int j = 0; j < 8; ++j) {
                znp[s] = fmaf(zv[j], zv[j], znp[s]);
                float tt = -2.f * zv[j];
                _Float16 h = (_Float16)tt;
                Ahi[s][ks][j] = h;
                Alo[s][ks][j] = (_Float16)(tt - (float)h);
            }
        }
    }
    // znorm per row, kept in registers: after the two xors every lane holds
    // the full ||z_row||^2 for row s*16 + m16 of this wave.
#pragma unroll
    for (int s = 0; s < NSUB; ++s) {
        znp[s] += __shfl_xor(znp[s], 16, 64);
        znp[s] += __shfl_xor(znp[s], 32, 64);
    }

    float bestv[NSUB][4];
    int besti[NSUB][4];
#pragma unroll
    for (int s = 0; s < NSUB; ++s)
#pragma unroll
        for (int r = 0; r < 4; ++r) {
            bestv[s][r] = FLT_MAX;
            besti[s][r] = 0;
        }

    __syncthreads();  // s_enorm visible (only barrier before the epilogue)

    float eA = s_enorm[m16], eB = 0.f;

    // Step body: 24 MFMAs over 6 INDEPENDENT chains (hh/hl/lh x subtile);
    // loads for ST+1 into (NH,NL,NE) issue first and land under the MFMA/
    // argmin (no barriers; compiler places the counted vmcnt at first use).
    // Round-robin issue order keeps same-chain spacing at 6 slots.
#define BODY(ST, CH, CL, CE, NH, NL, NE, DO_NEXT)                                           \
    {                                                                                       \
        if (DO_NEXT) {                                                                      \
            LOADF((ST) + 1, NH, NL)                                                         \
            NE = s_enorm[((ST) + 1) * CODES_PER_TILE + m16];                                \
        }                                                                                   \
        f32x4 hh0 = {CE, CE, CE, CE}, hh1 = {CE, CE, CE, CE};                               \
        f32x4 hl0 = {0.f, 0.f, 0.f, 0.f}, hl1 = {0.f, 0.f, 0.f, 0.f};                       \
        f32x4 lh0 = {0.f, 0.f, 0.f, 0.f}, lh1 = {0.f, 0.f, 0.f, 0.f};                       \
        __builtin_amdgcn_s_setprio(1);                                                      \
        _Pragma("unroll") for (int ks = 0; ks < KSTEPS; ++ks) {                             \
            hh0 = __builtin_amdgcn_mfma_f32_16x16x32_f16(Ahi[0][ks], CH[ks], hh0, 0, 0, 0); \
            hh1 = __builtin_amdgcn_mfma_f32_16x16x32_f16(Ahi[1][ks], CH[ks], hh1, 0, 0, 0); \
            hl0 = __builtin_amdgcn_mfma_f32_16x16x32_f16(Ahi[0][ks], CL[ks], hl0, 0, 0, 0); \
            hl1 = __builtin_amdgcn_mfma_f32_16x16x32_f16(Ahi[1][ks], CL[ks], hl1, 0, 0, 0); \
            lh0 = __builtin_amdgcn_mfma_f32_16x16x32_f16(Alo[0][ks], CH[ks], lh0, 0, 0, 0); \
            lh1 = __builtin_amdgcn_mfma_f32_16x16x32_f16(Alo[1][ks], CH[ks], lh1, 0, 0, 0); \
        }                                                                                   \
        __builtin_amdgcn_s_setprio(0);                                                      \
        const int n_ = (ST)*CODES_PER_TILE + m16;                                           \
        /* C layout: col = lane&15 (code), row = quad*4 + r */                              \
        _Pragma("unroll") for (int r = 0; r < 4; ++r) {                                     \
            const float d0 = (hh0[r] + hl0[r]) + lh0[r];                                    \
            const float d1 = (hh1[r] + hl1[r]) + lh1[r];                                    \
            if (d0 < bestv[0][r]) { bestv[0][r] = d0; besti[0][r] = n_; }                   \
            if (d1 < bestv[1][r]) { bestv[1][r] = d1; besti[1][r] = n_; }                   \
        }                                                                                   \
    }

    for (int st = 0; st < NSTEPS - 2; st += 2) {
        BODY(st, FAh, FAl, eA, FBh, FBl, eB, 1)
        BODY(st + 1, FBh, FBl, eB, FAh, FAl, eA, 1)
    }
    BODY(NSTEPS - 2, FAh, FAl, eA, FBh, FBl, eB, 1)
    BODY(NSTEPS - 1, FBh, FBl, eB, FAh, FAl, eA, 0)
#undef BODY
#undef LOADF

    // ---- in-wave argmin across the 16 m16-lanes (xor butterflies stay
    // in-quad; lexicographic (v,i) merge == global first-index rule; after the
    // butterfly ALL 16 lanes of a group hold the winner)
#pragma unroll
    for (int s = 0; s < NSUB; ++s)
#pragma unroll
        for (int r = 0; r < 4; ++r) {
            float v = bestv[s][r];
            int i = besti[s][r];
#pragma unroll
            for (int m = 1; m <= 8; m <<= 1) {
                float ov = __shfl_xor(v, m, 64);
                int oi = __shfl_xor(i, m, 64);
                if (ov < v || (ov == v && oi < i)) {
                    v = ov;
                    i = oi;
                }
            }
            bestv[s][r] = v;
            besti[s][r] = i;
        }

    // winner lane per quad owns rows quad*4+r (+s*16); loss partial uses
    // znorm shfl'd from the lane whose m16 == quad*4+r.
    float lp = 0.f;
#pragma unroll
    for (int s = 0; s < NSUB; ++s)
#pragma unroll
        for (int r = 0; r < 4; ++r) {
            const float zz = __shfl(znp[s], quad * 4 + r, 16);
            if (m16 == 0) {
                const int row = wave * ROWS_PER_WAVE + s * 16 + quad * 4 + r;
                s_ind[row] = besti[s][r];
                lp += zz + bestv[s][r];  // ||z-E||^2 = ||z||^2 + dist'
            }
        }
    lp += __shfl_xor(lp, 16, 64);  // lanes {0,16,32,48} hold partials
    lp += __shfl_xor(lp, 32, 64);
    if (lane == 0) s_wsum[wave] = lp;
    __syncthreads();
    if (t == 0)
        atomicAdd(loss, (s_wsum[0] + s_wsum[1] + s_wsum[2] + s_wsum[3]) * LOSS_SCALE);

    // ---- gather-write z_q (STE forward == z_q), float4 coalesced, E is L2-hot
    const float4* E4 = (const float4*)E;
    float4* out4 = (float4*)(out + (size_t)blockIdx.x * (MTILE * DIM));
#pragma unroll
    for (int i = 0; i < (MTILE * DIM) / (256 * 4); ++i) {
        const int f = t + i * 256;  // float4 index within tile
        const int r = f >> 5;       // 32 float4 per row
        const int d = f & 31;
        out4[f] = E4[(size_t)s_ind[r] * 32 + d];
    }
}

extern "C" void kernel_launch(void* const* d_in, const int* in_sizes, int n_in,
                              void* d_out, int out_size, void* d_ws, size_t ws_size,
                              hipStream_t stream) {
    const float* z = (const float*)d_in[0];  // [BN,128] fp32
    const float* E = (const float*)d_in[1];  // [1024,128] fp32
    float* out = (float*)d_out;              // [BN*128] z_q + [1] loss
    float* loss = out + (size_t)(out_size - 1);
    _Float16* Epk = (_Float16*)d_ws;                          // 512 KB packed image
    float* enorm = (float*)((char*)d_ws + (size_t)NCODES * DIM * 2 * sizeof(_Float16));  // 4 KB
    const int BN = in_sizes[0] / DIM;

    prep_kernel<<<NCODES, 128, 0, stream>>>(E, Epk, enorm, loss);
    vq_kernel<<<BN / MTILE, 256, 0, stream>>>(z, Epk, enorm, E, out, loss);
}